// Round 14
// baseline (64.464 us; speedup 1.0000x reference)
//
#include <hip/hip_runtime.h>
#include <hip/hip_bf16.h>

#define B_SZ   2048
#define F_IN   1024
#define R_EMB  1024
#define F_OUT  1024
#define F_MID  2048
#define NNZ_E  65536
#define NNZ_W  131072
#define NNZ_B  512

typedef __bf16 bf16x8 __attribute__((ext_vector_type(8)));
typedef float  f32x4  __attribute__((ext_vector_type(4)));

__device__ inline void gload16(const void* g, void* l) {
    __builtin_amdgcn_global_load_lds(
        (const __attribute__((address_space(1))) void*)g,
        (__attribute__((address_space(3))) void*)l, 16, 0, 0);
}

__device__ inline ushort f2bf(float v) {
    __hip_bfloat16 h = __float2bfloat16(v);
    return *reinterpret_cast<ushort*>(&h);
}

__device__ inline float bf2f(ushort u) {
    uint w = (uint)u << 16;
    float f;
    __builtin_memcpy(&f, &w, 4);
    return f;
}

// bf16 scatter-add via 32-bit CAS on the containing word (handles duplicate
// (r,c) entries and false sharing; ~6% fill -> ~1 CAS iteration expected).
__device__ inline void bf16_scatter_add(ushort* addr, float val) {
    uint* word = (uint*)((uintptr_t)addr & ~(uintptr_t)3);
    const bool hi = ((uintptr_t)addr & 2) != 0;
    uint old = __hip_atomic_load(word, __ATOMIC_RELAXED, __HIP_MEMORY_SCOPE_AGENT);
    while (true) {
        ushort cur = hi ? (ushort)(old >> 16) : (ushort)(old & 0xffffu);
        ushort nv  = f2bf(bf2f(cur) + val);
        uint neww  = hi ? ((old & 0x0000ffffu) | ((uint)nv << 16))
                        : ((old & 0xffff0000u) | (uint)nv);
        uint prev = atomicCAS(word, old, neww);
        if (prev == old) break;
        old = prev;
    }
}

// Launch 1: zero (biasd|Ebf|Wbf, contiguous 6 MB + 4 KB) || x f32->bf16 into
// x2 left half.  Disjoint writes -> safe in one kernel.
__global__ void k_zerocvt(float4* __restrict__ zbase,   // = biasd
                          const float4* __restrict__ x, ushort* __restrict__ x2) {
    int b = blockIdx.x, t = threadIdx.x;
    if (b < 1537) {                          // zero: 393472 float4
        int i = b * 256 + t;
        if (i < 393472) zbase[i] = make_float4(0.f, 0.f, 0.f, 0.f);
    } else {                                 // x convert: 524288 float4
        int i = (b - 1537) * 256 + t;
        int row = i >> 8, c4 = i & 255;      // 256 float4 per row of 1024
        float4 v = x[i];
        ((ushort4*)x2)[(size_t)row * (F_MID / 4) + c4] =
            make_ushort4(f2bf(v.x), f2bf(v.y), f2bf(v.z), f2bf(v.w));
    }
}

// Launch 2: all sparse scatters (E, W direct-to-bf16; bias f32).
__global__ void k_scatter(const int* __restrict__ er, const int* __restrict__ ec,
                          const float* __restrict__ ev,
                          const int* __restrict__ wr_, const int* __restrict__ wc_,
                          const float* __restrict__ wv,
                          const int* __restrict__ bi, const float* __restrict__ bv,
                          ushort* __restrict__ Ebf, ushort* __restrict__ Wbf,
                          float* __restrict__ biasd) {
    int b = blockIdx.x, t = threadIdx.x;
    if (b < NNZ_E / 256) {
        int i = b * 256 + t;
        bf16_scatter_add(&Ebf[(size_t)er[i] * F_IN + ec[i]], ev[i]);
    } else if (b < NNZ_E / 256 + NNZ_W / 256) {
        int i = (b - NNZ_E / 256) * 256 + t;
        bf16_scatter_add(&Wbf[(size_t)wr_[i] * F_MID + wc_[i]], wv[i]);
    } else {
        int i = (b - NNZ_E / 256 - NNZ_W / 256) * 256 + t;
        if (i < NNZ_B) atomicAdd(&biasd[bi[i]], bv[i]);
    }
}

// R6 64x64 GEMM core (2-phase dbuf, XOR chunk-swizzle, 4 waves of 32x32 wave
// tiles, 16x16x32 MFMA), templated on MODE:
//   MODE 0: h = relu(x @ E^T),        K=1024  -> bf16 into x2 right half
//   MODE 1: out = x2 @ W_full^T + b,  K=2048  -> f32, written ONCE (no RMW;
//           R13 structure paid an extra 16 MB out read+write via gemmB RMW)
template <int MODE>
__global__ __launch_bounds__(256)
void k_gemm(const ushort* __restrict__ x2,   // [2048][2048] bf16
            const ushort* __restrict__ Bmat, // MODE 0: Ebf; MODE 1: Wbf
            const float* __restrict__ biasd,
            float* __restrict__ out,
            ushort* __restrict__ hOut)       // = x2 + F_IN
{
    constexpr int BK = 64;
    constexpr int NT  = (MODE == 0) ? 16 : 32;
    constexpr int LDB = (MODE == 0) ? F_IN : F_MID;
    __shared__ ushort lds[2][2][64 * 64];    // 32 KB
    const int tid = threadIdx.x;
    const int w = tid >> 6, l = tid & 63;
    const int wr = w >> 1, wc = w & 1;
    const int la = l & 15;

    const int blk = blockIdx.x;              // 512 blocks
    const int sw  = (blk & 7) * 64 + (blk >> 3);   // XCD chunk swizzle
    const int m0  = (sw >> 4) * 64;
    const int n0  = (sw & 15) * 64;

    const int srow = w * 8 + (l >> 3);
    const int ldst = w * 512 + l * 8;

    f32x4 acc[2][2] = {};

    #define STAGE(buf, k0)                                                      \
        _Pragma("unroll")                                                       \
        for (int i = 0; i < 2; ++i) {                                           \
            int row = i * 32 + srow;                                            \
            int scol = (k0) + ((((l & 7) ^ (row & 7))) << 3);                   \
            gload16(x2   + (size_t)(m0 + row) * F_MID + scol,                   \
                    &lds[buf][0][i * 2048 + ldst]);                             \
            gload16(Bmat + (size_t)(n0 + row) * LDB + scol,                     \
                    &lds[buf][1][i * 2048 + ldst]);                             \
        }

    STAGE(0, 0);
    __syncthreads();

    for (int t = 0; t < NT; ++t) {
        const int cur = t & 1;
        if (t + 1 < NT) STAGE(cur ^ 1, (t + 1) * BK);

        const ushort* sA = &lds[cur][0][0];
        const ushort* sB = &lds[cur][1][0];
        #pragma unroll
        for (int ks = 0; ks < 2; ++ks) {
            const int k8 = ks * 4 + (l >> 4);
            bf16x8 af[2], bg[2];
            #pragma unroll
            for (int m = 0; m < 2; ++m) {
                int row = wr * 32 + m * 16 + la;
                af[m] = *(const bf16x8*)(sA + row * BK + ((k8 ^ (row & 7)) << 3));
            }
            #pragma unroll
            for (int n = 0; n < 2; ++n) {
                int row = wc * 32 + n * 16 + la;
                bg[n] = *(const bf16x8*)(sB + row * BK + ((k8 ^ (row & 7)) << 3));
            }
            #pragma unroll
            for (int m = 0; m < 2; ++m)
                #pragma unroll
                for (int n = 0; n < 2; ++n)
                    acc[m][n] = __builtin_amdgcn_mfma_f32_16x16x32_bf16(
                        af[m], bg[n], acc[m][n], 0, 0, 0);
        }
        __syncthreads();
    }
    #undef STAGE

    // C/D layout (verified m89/m91): col = lane&15, row = (lane>>4)*4 + reg.
    const int lr = (l >> 4) * 4;
    #pragma unroll
    for (int m = 0; m < 2; ++m) {
        #pragma unroll
        for (int n = 0; n < 2; ++n) {
            const int col = n0 + wc * 32 + n * 16 + la;
            if (MODE == 0) {
                #pragma unroll
                for (int j = 0; j < 4; ++j) {
                    int row = m0 + wr * 32 + m * 16 + lr + j;
                    hOut[(size_t)row * F_MID + col] = f2bf(fmaxf(acc[m][n][j], 0.f));
                }
            } else {
                const float bv = biasd[col];
                #pragma unroll
                for (int j = 0; j < 4; ++j) {
                    int row = m0 + wr * 32 + m * 16 + lr + j;
                    out[(size_t)row * F_OUT + col] = acc[m][n][j] + bv;
                }
            }
        }
    }
}

extern "C" void kernel_launch(void* const* d_in, const int* in_sizes, int n_in,
                              void* d_out, int out_size, void* d_ws, size_t ws_size,
                              hipStream_t stream) {
    const float* x          = (const float*)d_in[0];
    const int*   embed_rows = (const int*)  d_in[1];
    const int*   embed_cols = (const int*)  d_in[2];
    const float* embed_vals = (const float*)d_in[3];
    const int*   w_rows     = (const int*)  d_in[4];
    const int*   w_cols     = (const int*)  d_in[5];
    const float* w_vals     = (const float*)d_in[6];
    const int*   bias_idx   = (const int*)  d_in[7];
    const float* bias_vals  = (const float*)d_in[8];
    float* out = (float*)d_out;

    // Workspace layout (~26 MB):
    //   [0, 8M)          x2 bf16 [2048][2048]  (left = x, right = relu h)
    //   [20M, 20M+4K)    bias f32 [1024]
    //   [20M+4K, 22M+4K) E_bf16 [1024][1024]
    //   [22M+4K, 26M+4K) W_bf16 [1024][2048]
    //   (bias|Ebf|Wbf contiguous -> one 6MB+4KB zero range)
    char* ws = (char*)d_ws;
    ushort* x2    = (ushort*)ws;
    float*  biasd = (float*)(ws + (20u << 20));
    ushort* Ebf   = (ushort*)(ws + (20u << 20) + 4096);
    ushort* Wbf   = (ushort*)(ws + (22u << 20) + 4096);

    // 1. zero (bias|Ebf|Wbf) || x-cvt  (disjoint writes, one launch)
    k_zerocvt<<<1537 + 2048, 256, 0, stream>>>((float4*)biasd,
                                               (const float4*)x, x2);

    // 2. sparse scatters (E, W direct-bf16 CAS; bias f32)
    k_scatter<<<NNZ_E / 256 + NNZ_W / 256 + (NNZ_B + 255) / 256, 256, 0, stream>>>(
        embed_rows, embed_cols, embed_vals,
        w_rows, w_cols, w_vals,
        bias_idx, bias_vals, Ebf, Wbf, biasd);

    // 3. gemmH: h = relu(x @ E^T)  (K=1024, 512 blocks)
    k_gemm<0><<<512, 256, 0, stream>>>(x2, Ebf, biasd, out, x2 + F_IN);

    // 4. gemmOut: out = x2 @ W_full^T + bias  (K=2048, single pass, no RMW)
    k_gemm<1><<<512, 256, 0, stream>>>(x2, Wbf, biasd, out, x2 + F_IN);
}

// Round 15
// 61.447 us; speedup vs baseline: 1.0491x; 1.0491x over previous
//
#include <hip/hip_runtime.h>
#include <hip/hip_bf16.h>

#define B_SZ   2048
#define F_IN   1024
#define R_EMB  1024
#define F_OUT  1024
#define F_MID  2048
#define NNZ_E  65536
#define NNZ_W  131072
#define NNZ_B  512

typedef __bf16 bf16x8 __attribute__((ext_vector_type(8)));
typedef float  f32x4  __attribute__((ext_vector_type(4)));

__device__ inline void gload16(const void* g, void* l) {
    __builtin_amdgcn_global_load_lds(
        (const __attribute__((address_space(1))) void*)g,
        (__attribute__((address_space(3))) void*)l, 16, 0, 0);
}

__device__ inline ushort f2bf(float v) {
    __hip_bfloat16 h = __float2bfloat16(v);
    return *reinterpret_cast<ushort*>(&h);
}

__device__ inline float bf2f(ushort u) {
    uint w = (uint)u << 16;
    float f;
    __builtin_memcpy(&f, &w, 4);
    return f;
}

// bf16 scatter-add via 32-bit CAS on the containing word (handles duplicate
// (r,c) entries and false sharing; ~6% fill -> ~1 CAS iteration expected).
__device__ inline void bf16_scatter_add(ushort* addr, float val) {
    uint* word = (uint*)((uintptr_t)addr & ~(uintptr_t)3);
    const bool hi = ((uintptr_t)addr & 2) != 0;
    uint old = __hip_atomic_load(word, __ATOMIC_RELAXED, __HIP_MEMORY_SCOPE_AGENT);
    while (true) {
        ushort cur = hi ? (ushort)(old >> 16) : (ushort)(old & 0xffffu);
        ushort nv  = f2bf(bf2f(cur) + val);
        uint neww  = hi ? ((old & 0x0000ffffu) | ((uint)nv << 16))
                        : ((old & 0xffff0000u) | (uint)nv);
        uint prev = atomicCAS(word, old, neww);
        if (prev == old) break;
        old = prev;
    }
}

__global__ void k_zero4(float4* __restrict__ p, int n) {
    int i = blockIdx.x * blockDim.x + threadIdx.x;
    if (i < n) p[i] = make_float4(0.f, 0.f, 0.f, 0.f);
}

// One launch: x f32->bf16 into x2 left half, E/W CAS-scatter directly to bf16
// dense, bias f32 scatter.  Blocks partitioned by range.  (R13-proven.)
__global__ void k_prep(const float4* __restrict__ x, ushort* __restrict__ x2,
                       const int* __restrict__ er, const int* __restrict__ ec,
                       const float* __restrict__ ev,
                       const int* __restrict__ wr_, const int* __restrict__ wc_,
                       const float* __restrict__ wv,
                       const int* __restrict__ bi, const float* __restrict__ bv,
                       ushort* __restrict__ Ebf, ushort* __restrict__ Wbf,
                       float* __restrict__ biasd) {
    int b = blockIdx.x, t = threadIdx.x;
    if (b < 2048) {                          // x convert: 524288 float4
        int i = b * 256 + t;
        int row = i >> 8, c4 = i & 255;      // 256 float4 per row of 1024
        float4 v = x[i];
        ((ushort4*)x2)[(size_t)row * (F_MID / 4) + c4] =
            make_ushort4(f2bf(v.x), f2bf(v.y), f2bf(v.z), f2bf(v.w));
    } else if (b < 2048 + NNZ_E / 256) {     // E scatter
        int i = (b - 2048) * 256 + t;
        bf16_scatter_add(&Ebf[(size_t)er[i] * F_IN + ec[i]], ev[i]);
    } else if (b < 2048 + NNZ_E / 256 + NNZ_W / 256) {   // W scatter
        int i = (b - 2048 - NNZ_E / 256) * 256 + t;
        bf16_scatter_add(&Wbf[(size_t)wr_[i] * F_MID + wc_[i]], wv[i]);
    } else {                                 // bias scatter: 2 blocks
        int i = (b - 2048 - NNZ_E / 256 - NNZ_W / 256) * 256 + t;
        bf16_scatter_add(nullptr, 0.f);      // never taken; keep structure simple
    }
}

// bias scatter folded here to keep k_prep branchless-simple above.
__global__ void k_prep_tail(const int* __restrict__ bi, const float* __restrict__ bv,
                            float* __restrict__ biasd) {
    int i = blockIdx.x * blockDim.x + threadIdx.x;
    if (i < NNZ_B) atomicAdd(&biasd[bi[i]], bv[i]);
}

// GEMM-A' (dual-B fusion, R13-proven): one block per (m0,n0) stages its A-tile
// once and computes BOTH h = relu(x @ E^T) and out = x @ W_L^T + bias.
// 64x64x64 tiles, 2-phase dbuf, XOR chunk-swizzle, 4 waves of 32x32 wave
// tiles, 16x16x32 MFMA.  af shared across both products: 6 ds_reads / 8 MFMA.
__global__ __launch_bounds__(256)
void k_gemmA(const ushort* __restrict__ x2,   // [2048][2048] bf16 (left half = x)
             const ushort* __restrict__ Ebf,  // [1024][1024] bf16
             const ushort* __restrict__ Wbf,  // [1024][2048] bf16
             const float* __restrict__ biasd, // [1024]
             float* __restrict__ out,         // [2048][1024] f32
             ushort* __restrict__ hOut)       // = x2 + F_IN
{
    constexpr int BK = 64, NT = 16;
    __shared__ ushort lds[2][3][64 * 64];     // [buf][A|BE|BW], 48 KB
    const int tid = threadIdx.x;
    const int w = tid >> 6, l = tid & 63;
    const int wr = w >> 1, wc = w & 1;
    const int la = l & 15;

    const int blk = blockIdx.x;               // 512 blocks
    const int sw  = (blk & 7) * 64 + (blk >> 3);   // XCD chunk swizzle
    const int m0  = (sw >> 4) * 64;
    const int n0  = (sw & 15) * 64;

    const int srow = w * 8 + (l >> 3);
    const int ldst = w * 512 + l * 8;

    f32x4 accE[2][2] = {}, accW[2][2] = {};

    #define STAGE(buf, k0)                                                      \
        _Pragma("unroll")                                                       \
        for (int i = 0; i < 2; ++i) {                                           \
            int row = i * 32 + srow;                                            \
            int scol = (k0) + ((((l & 7) ^ (row & 7))) << 3);                   \
            gload16(x2  + (size_t)(m0 + row) * F_MID + scol,                    \
                    &lds[buf][0][i * 2048 + ldst]);                             \
            gload16(Ebf + (size_t)(n0 + row) * F_IN + scol,                     \
                    &lds[buf][1][i * 2048 + ldst]);                             \
            gload16(Wbf + (size_t)(n0 + row) * F_MID + scol,                    \
                    &lds[buf][2][i * 2048 + ldst]);                             \
        }

    STAGE(0, 0);
    __syncthreads();

    for (int t = 0; t < NT; ++t) {
        const int cur = t & 1;
        if (t + 1 < NT) STAGE(cur ^ 1, (t + 1) * BK);

        const ushort* sA  = &lds[cur][0][0];
        const ushort* sBE = &lds[cur][1][0];
        const ushort* sBW = &lds[cur][2][0];
        #pragma unroll
        for (int ks = 0; ks < 2; ++ks) {
            const int k8 = ks * 4 + (l >> 4);
            bf16x8 af[2], be[2], bw[2];
            #pragma unroll
            for (int m = 0; m < 2; ++m) {
                int row = wr * 32 + m * 16 + la;
                af[m] = *(const bf16x8*)(sA + row * BK + ((k8 ^ (row & 7)) << 3));
            }
            #pragma unroll
            for (int n = 0; n < 2; ++n) {
                int row = wc * 32 + n * 16 + la;
                be[n] = *(const bf16x8*)(sBE + row * BK + ((k8 ^ (row & 7)) << 3));
                bw[n] = *(const bf16x8*)(sBW + row * BK + ((k8 ^ (row & 7)) << 3));
            }
            #pragma unroll
            for (int m = 0; m < 2; ++m)
                #pragma unroll
                for (int n = 0; n < 2; ++n) {
                    accE[m][n] = __builtin_amdgcn_mfma_f32_16x16x32_bf16(
                        af[m], be[n], accE[m][n], 0, 0, 0);
                    accW[m][n] = __builtin_amdgcn_mfma_f32_16x16x32_bf16(
                        af[m], bw[n], accW[m][n], 0, 0, 0);
                }
        }
        __syncthreads();
    }
    #undef STAGE

    // C/D layout (verified m89/m91): col = lane&15, row = (lane>>4)*4 + reg.
    const int lr = (l >> 4) * 4;
    #pragma unroll
    for (int m = 0; m < 2; ++m) {
        #pragma unroll
        for (int n = 0; n < 2; ++n) {
            const int col = n0 + wc * 32 + n * 16 + la;
            const float bv = biasd[col];
            #pragma unroll
            for (int j = 0; j < 4; ++j) {
                const int row = m0 + wr * 32 + m * 16 + lr + j;
                hOut[(size_t)row * F_MID + col] = f2bf(fmaxf(accE[m][n][j], 0.f));
                out[(size_t)row * F_OUT + col]  = accW[m][n][j] + bv;
            }
        }
    }
}

// GEMM-B: out += h @ W_R^T, SPLIT-K=2 (R14 lesson: serial K-depth is the
// lever, not RMW traffic).  1024 blocks = 4 blocks/CU, 8 K-tiles each,
// combined via f32 atomics (reorder noise ~1e-6 << 0.113 threshold; R8-proven).
__global__ __launch_bounds__(256)
void k_gemmB(const ushort* __restrict__ x2,   // h = x2 + F_IN
             const ushort* __restrict__ Wbf,
             float* __restrict__ out)
{
    constexpr int BK = 64, NT = 8;             // K=512 per split
    __shared__ ushort lds[2][2][64 * 64];
    const int tid = threadIdx.x;
    const int w = tid >> 6, l = tid & 63;
    const int wr = w >> 1, wc = w & 1;
    const int la = l & 15;

    const int blk = blockIdx.x;                // 1024 blocks
    const int sw  = (blk & 7) * 128 + (blk >> 3);   // bijective XCD swizzle
    const int ksl = sw >> 9;                   // K-slice 0/1
    const int inr = sw & 511;
    const int m0  = (inr >> 4) * 64;
    const int n0  = (inr & 15) * 64;
    const int kbase = ksl * 512;

    const ushort* A  = x2 + F_IN;
    const ushort* Bm = Wbf + F_IN;

    const int srow = w * 8 + (l >> 3);
    const int ldst = w * 512 + l * 8;

    f32x4 acc[2][2] = {};

    #define STAGE(buf, k0)                                                      \
        _Pragma("unroll")                                                       \
        for (int i = 0; i < 2; ++i) {                                           \
            int row = i * 32 + srow;                                            \
            int scol = (k0) + ((((l & 7) ^ (row & 7))) << 3);                   \
            gload16(A  + (size_t)(m0 + row) * F_MID + scol,                     \
                    &lds[buf][0][i * 2048 + ldst]);                             \
            gload16(Bm + (size_t)(n0 + row) * F_MID + scol,                     \
                    &lds[buf][1][i * 2048 + ldst]);                             \
        }

    STAGE(0, kbase);
    __syncthreads();

    for (int t = 0; t < NT; ++t) {
        const int cur = t & 1;
        if (t + 1 < NT) STAGE(cur ^ 1, kbase + (t + 1) * BK);

        const ushort* sA = &lds[cur][0][0];
        const ushort* sB = &lds[cur][1][0];
        #pragma unroll
        for (int ks = 0; ks < 2; ++ks) {
            const int k8 = ks * 4 + (l >> 4);
            bf16x8 af[2], bg[2];
            #pragma unroll
            for (int m = 0; m < 2; ++m) {
                int row = wr * 32 + m * 16 + la;
                af[m] = *(const bf16x8*)(sA + row * BK + ((k8 ^ (row & 7)) << 3));
            }
            #pragma unroll
            for (int n = 0; n < 2; ++n) {
                int row = wc * 32 + n * 16 + la;
                bg[n] = *(const bf16x8*)(sB + row * BK + ((k8 ^ (row & 7)) << 3));
            }
            #pragma unroll
            for (int m = 0; m < 2; ++m)
                #pragma unroll
                for (int n = 0; n < 2; ++n)
                    acc[m][n] = __builtin_amdgcn_mfma_f32_16x16x32_bf16(
                        af[m], bg[n], acc[m][n], 0, 0, 0);
        }
        __syncthreads();
    }
    #undef STAGE

    const int lr = (l >> 4) * 4;
    #pragma unroll
    for (int m = 0; m < 2; ++m) {
        #pragma unroll
        for (int n = 0; n < 2; ++n) {
            const int col = n0 + wc * 32 + n * 16 + la;
            #pragma unroll
            for (int j = 0; j < 4; ++j) {
                const int row = m0 + wr * 32 + m * 16 + lr + j;
                unsafeAtomicAdd(&out[(size_t)row * F_OUT + col], acc[m][n][j]);
            }
        }
    }
}

extern "C" void kernel_launch(void* const* d_in, const int* in_sizes, int n_in,
                              void* d_out, int out_size, void* d_ws, size_t ws_size,
                              hipStream_t stream) {
    const float* x          = (const float*)d_in[0];
    const int*   embed_rows = (const int*)  d_in[1];
    const int*   embed_cols = (const int*)  d_in[2];
    const float* embed_vals = (const float*)d_in[3];
    const int*   w_rows     = (const int*)  d_in[4];
    const int*   w_cols     = (const int*)  d_in[5];
    const float* w_vals     = (const float*)d_in[6];
    const int*   bias_idx   = (const int*)  d_in[7];
    const float* bias_vals  = (const float*)d_in[8];
    float* out = (float*)d_out;

    // Workspace layout (~26 MB):
    //   [0, 8M)          x2 bf16 [2048][2048]  (left = x, right = relu h)
    //   [20M, 20M+4K)    bias f32 [1024]
    //   [20M+4K, 22M+4K) E_bf16 [1024][1024]
    //   [22M+4K, 26M+4K) W_bf16 [1024][2048]
    //   (bias|Ebf|Wbf contiguous -> one 6MB+4KB zero range)
    char* ws = (char*)d_ws;
    ushort* x2    = (ushort*)ws;
    float*  biasd = (float*)(ws + (20u << 20));
    ushort* Ebf   = (ushort*)(ws + (20u << 20) + 4096);
    ushort* Wbf   = (ushort*)(ws + (22u << 20) + 4096);

    // 1. zero biasd | Ebf | Wbf (contiguous 6 MB + 4 KB = 393472 float4)
    k_zero4<<<1537, 256, 0, stream>>>((float4*)biasd, 393472);

    // 2. x-cvt + direct-bf16 CAS scatter (E, W); bias in a tiny tail kernel
    //    on the same stream (2 blocks; negligible).
    k_prep<<<2048 + NNZ_E / 256 + NNZ_W / 256, 256, 0, stream>>>(
        (const float4*)x, x2,
        embed_rows, embed_cols, embed_vals,
        w_rows, w_cols, w_vals,
        bias_idx, bias_vals, Ebf, Wbf, biasd);
    k_prep_tail<<<2, 256, 0, stream>>>(bias_idx, bias_vals, biasd);

    // 3. GEMM-A': dual-B fused  {h = relu(x @ E^T)} + {out = x @ W_L^T + bias}
    k_gemmA<<<512, 256, 0, stream>>>(x2, Ebf, Wbf, biasd, out, x2 + F_IN);

    // 4. GEMM-B: out += h @ W_R^T  (split-K=2, 1024 blocks, f32 atomics)
    k_gemmB<<<1024, 256, 0, stream>>>(x2, Wbf, out);
}

// Round 16
// 50.955 us; speedup vs baseline: 1.2651x; 1.2059x over previous
//
#include <hip/hip_runtime.h>
#include <hip/hip_bf16.h>

#define B_SZ   2048
#define F_IN   1024
#define R_EMB  1024
#define F_OUT  1024
#define F_MID  2048
#define NNZ_E  65536
#define NNZ_W  131072
#define NNZ_B  512

typedef __bf16 bf16x8 __attribute__((ext_vector_type(8)));
typedef float  f32x16 __attribute__((ext_vector_type(16)));

__device__ inline void gload16(const void* g, void* l) {
    __builtin_amdgcn_global_load_lds(
        (const __attribute__((address_space(1))) void*)g,
        (__attribute__((address_space(3))) void*)l, 16, 0, 0);
}

__device__ inline ushort f2bf(float v) {
    __hip_bfloat16 h = __float2bfloat16(v);
    return *reinterpret_cast<ushort*>(&h);
}

__device__ inline float bf2f(ushort u) {
    uint w = (uint)u << 16;
    float f;
    __builtin_memcpy(&f, &w, 4);
    return f;
}

// bf16 scatter-add via 32-bit CAS on the containing word (handles duplicate
// (r,c) entries and false sharing; ~6% fill -> ~1 CAS iteration expected).
__device__ inline void bf16_scatter_add(ushort* addr, float val) {
    uint* word = (uint*)((uintptr_t)addr & ~(uintptr_t)3);
    const bool hi = ((uintptr_t)addr & 2) != 0;
    uint old = __hip_atomic_load(word, __ATOMIC_RELAXED, __HIP_MEMORY_SCOPE_AGENT);
    while (true) {
        ushort cur = hi ? (ushort)(old >> 16) : (ushort)(old & 0xffffu);
        ushort nv  = f2bf(bf2f(cur) + val);
        uint neww  = hi ? ((old & 0x0000ffffu) | ((uint)nv << 16))
                        : ((old & 0xffff0000u) | (uint)nv);
        uint prev = atomicCAS(word, old, neww);
        if (prev == old) break;
        old = prev;
    }
}

__global__ void k_zero4(float4* __restrict__ p, int n) {
    int i = blockIdx.x * blockDim.x + threadIdx.x;
    if (i < n) p[i] = make_float4(0.f, 0.f, 0.f, 0.f);
}

// One launch: x f32->bf16 into x2 left half, E/W CAS-scatter directly to bf16
// dense, bias f32 scatter.  Blocks partitioned by range.  (R13-proven.)
__global__ void k_prep(const float4* __restrict__ x, ushort* __restrict__ x2,
                       const int* __restrict__ er, const int* __restrict__ ec,
                       const float* __restrict__ ev,
                       const int* __restrict__ wr_, const int* __restrict__ wc_,
                       const float* __restrict__ wv,
                       const int* __restrict__ bi, const float* __restrict__ bv,
                       ushort* __restrict__ Ebf, ushort* __restrict__ Wbf,
                       float* __restrict__ biasd) {
    int b = blockIdx.x, t = threadIdx.x;
    if (b < 2048) {                          // x convert: 524288 float4
        int i = b * 256 + t;
        int row = i >> 8, c4 = i & 255;      // 256 float4 per row of 1024
        float4 v = x[i];
        ((ushort4*)x2)[(size_t)row * (F_MID / 4) + c4] =
            make_ushort4(f2bf(v.x), f2bf(v.y), f2bf(v.z), f2bf(v.w));
    } else if (b < 2048 + NNZ_E / 256) {     // E scatter
        int i = (b - 2048) * 256 + t;
        bf16_scatter_add(&Ebf[(size_t)er[i] * F_IN + ec[i]], ev[i]);
    } else if (b < 2048 + NNZ_E / 256 + NNZ_W / 256) {   // W scatter
        int i = (b - 2048 - NNZ_E / 256) * 256 + t;
        bf16_scatter_add(&Wbf[(size_t)wr_[i] * F_MID + wc_[i]], wv[i]);
    } else {                                 // bias scatter: 2 blocks
        int i = (b - 2048 - NNZ_E / 256 - NNZ_W / 256) * 256 + t;
        if (i < NNZ_B) atomicAdd(&biasd[bi[i]], bv[i]);
    }
}

// GEMM-A' (dual-B fusion, R13 structure) with 32x32x16 MFMA:
// one block per (m0,n0) stages its A-tile once, computes BOTH
// h = relu(x @ E^T) and out = x @ W_L^T + bias.  64x64 block tile, BK=64,
// 4 waves of 32x32 wave tiles.  Per wave K-step: 12 ds_read_b128 -> 8 MFMA
// (same reads as R13, half the MFMA instructions, 64 vs 80 issue cycles).
// 2-phase dbuf, XOR chunk-swizzle, bijective XCD blockIdx swizzle.
__global__ __launch_bounds__(256)
void k_gemmA(const ushort* __restrict__ x2,   // [2048][2048] bf16 (left half = x)
             const ushort* __restrict__ Ebf,  // [1024][1024] bf16
             const ushort* __restrict__ Wbf,  // [1024][2048] bf16
             const float* __restrict__ biasd, // [1024]
             float* __restrict__ out,         // [2048][1024] f32
             ushort* __restrict__ hOut)       // = x2 + F_IN
{
    constexpr int BK = 64, NT = 16;
    __shared__ ushort lds[2][3][64 * 64];     // [buf][A|BE|BW], 48 KB
    const int tid = threadIdx.x;
    const int w = tid >> 6, l = tid & 63;
    const int wr = w >> 1, wc = w & 1;
    const int hi = l >> 5;                    // k-half within 16-wide sub-step

    const int blk = blockIdx.x;               // 512 blocks
    const int sw  = (blk & 7) * 64 + (blk >> 3);   // XCD chunk swizzle
    const int m0  = (sw >> 4) * 64;
    const int n0  = (sw & 15) * 64;

    const int arow = wr * 32 + (l & 31);      // A row within tile
    const int brow = wc * 32 + (l & 31);      // B row (output col) within tile
    const int xa = arow & 7, xb = brow & 7;

    const int srow = w * 8 + (l >> 3);
    const int ldst = w * 512 + l * 8;

    f32x16 accE = {}, accW = {};

    #define STAGE(buf, k0)                                                      \
        _Pragma("unroll")                                                       \
        for (int i = 0; i < 2; ++i) {                                           \
            int row = i * 32 + srow;                                            \
            int scol = (k0) + ((((l & 7) ^ (row & 7))) << 3);                   \
            gload16(x2  + (size_t)(m0 + row) * F_MID + scol,                    \
                    &lds[buf][0][i * 2048 + ldst]);                             \
            gload16(Ebf + (size_t)(n0 + row) * F_IN + scol,                     \
                    &lds[buf][1][i * 2048 + ldst]);                             \
            gload16(Wbf + (size_t)(n0 + row) * F_MID + scol,                    \
                    &lds[buf][2][i * 2048 + ldst]);                             \
        }

    STAGE(0, 0);
    __syncthreads();

    for (int t = 0; t < NT; ++t) {
        const int cur = t & 1;
        if (t + 1 < NT) STAGE(cur ^ 1, (t + 1) * BK);

        const ushort* sA  = &lds[cur][0][0];
        const ushort* sBE = &lds[cur][1][0];
        const ushort* sBW = &lds[cur][2][0];
        #pragma unroll
        for (int s = 0; s < 4; ++s) {          // 4 sub-steps of K=16
            const int c = s * 2 + hi;          // 8-elem chunk 0..7
            bf16x8 af = *(const bf16x8*)(sA  + arow * BK + ((c ^ xa) << 3));
            bf16x8 be = *(const bf16x8*)(sBE + brow * BK + ((c ^ xb) << 3));
            bf16x8 bw = *(const bf16x8*)(sBW + brow * BK + ((c ^ xb) << 3));
            accE = __builtin_amdgcn_mfma_f32_32x32x16_bf16(af, be, accE, 0, 0, 0);
            accW = __builtin_amdgcn_mfma_f32_32x32x16_bf16(af, bw, accW, 0, 0, 0);
        }
        __syncthreads();
    }
    #undef STAGE

    // C/D layout (verified m74/m101, R4-proven): col = lane&31,
    // row = (r&3) + 8*(r>>2) + 4*(lane>>5).
    const int col = n0 + wc * 32 + (l & 31);
    const int r0  = m0 + wr * 32 + 4 * hi;
    const float bv = biasd[col];
    #pragma unroll
    for (int r = 0; r < 16; ++r) {
        const int row = r0 + (r & 3) + 8 * (r >> 2);
        hOut[(size_t)row * F_MID + col] = f2bf(fmaxf(accE[r], 0.f));
        out[(size_t)row * F_OUT + col]  = accW[r] + bv;
    }
}

// GEMM-B: out += h @ W_R^T  (R13 structure, 32x32x16 MFMA, plain RMW,
// one block owns each tile; XCD swizzle).
__global__ __launch_bounds__(256)
void k_gemmB(const ushort* __restrict__ x2,   // h = x2 + F_IN
             const ushort* __restrict__ Wbf,
             float* __restrict__ out)
{
    constexpr int BK = 64, NT = 16;
    __shared__ ushort lds[2][2][64 * 64];     // 32 KB
    const int tid = threadIdx.x;
    const int w = tid >> 6, l = tid & 63;
    const int wr = w >> 1, wc = w & 1;
    const int hi = l >> 5;

    const int blk = blockIdx.x;
    const int sw  = (blk & 7) * 64 + (blk >> 3);
    const int m0  = (sw >> 4) * 64;
    const int n0  = (sw & 15) * 64;

    const ushort* A  = x2 + F_IN;
    const ushort* Bm = Wbf + F_IN;

    const int arow = wr * 32 + (l & 31);
    const int brow = wc * 32 + (l & 31);
    const int xa = arow & 7, xb = brow & 7;

    const int srow = w * 8 + (l >> 3);
    const int ldst = w * 512 + l * 8;

    f32x16 acc = {};

    #define STAGE(buf, k0)                                                      \
        _Pragma("unroll")                                                       \
        for (int i = 0; i < 2; ++i) {                                           \
            int row = i * 32 + srow;                                            \
            int scol = (k0) + ((((l & 7) ^ (row & 7))) << 3);                   \
            gload16(A  + (size_t)(m0 + row) * F_MID + scol,                     \
                    &lds[buf][0][i * 2048 + ldst]);                             \
            gload16(Bm + (size_t)(n0 + row) * F_MID + scol,                     \
                    &lds[buf][1][i * 2048 + ldst]);                             \
        }

    STAGE(0, 0);
    __syncthreads();

    for (int t = 0; t < NT; ++t) {
        const int cur = t & 1;
        if (t + 1 < NT) STAGE(cur ^ 1, (t + 1) * BK);

        const ushort* sA = &lds[cur][0][0];
        const ushort* sB = &lds[cur][1][0];
        #pragma unroll
        for (int s = 0; s < 4; ++s) {
            const int c = s * 2 + hi;
            bf16x8 af = *(const bf16x8*)(sA + arow * BK + ((c ^ xa) << 3));
            bf16x8 bg = *(const bf16x8*)(sB + brow * BK + ((c ^ xb) << 3));
            acc = __builtin_amdgcn_mfma_f32_32x32x16_bf16(af, bg, acc, 0, 0, 0);
        }
        __syncthreads();
    }
    #undef STAGE

    const int col = n0 + wc * 32 + (l & 31);
    const int r0  = m0 + wr * 32 + 4 * hi;
    #pragma unroll
    for (int r = 0; r < 16; ++r) {
        const int row = r0 + (r & 3) + 8 * (r >> 2);
        out[(size_t)row * F_OUT + col] += acc[r];
    }
}

extern "C" void kernel_launch(void* const* d_in, const int* in_sizes, int n_in,
                              void* d_out, int out_size, void* d_ws, size_t ws_size,
                              hipStream_t stream) {
    const float* x          = (const float*)d_in[0];
    const int*   embed_rows = (const int*)  d_in[1];
    const int*   embed_cols = (const int*)  d_in[2];
    const float* embed_vals = (const float*)d_in[3];
    const int*   w_rows     = (const int*)  d_in[4];
    const int*   w_cols     = (const int*)  d_in[5];
    const float* w_vals     = (const float*)d_in[6];
    const int*   bias_idx   = (const int*)  d_in[7];
    const float* bias_vals  = (const float*)d_in[8];
    float* out = (float*)d_out;

    // Workspace layout (~26 MB):
    //   [0, 8M)          x2 bf16 [2048][2048]  (left = x, right = relu h)
    //   [20M, 20M+4K)    bias f32 [1024]
    //   [20M+4K, 22M+4K) E_bf16 [1024][1024]
    //   [22M+4K, 26M+4K) W_bf16 [1024][2048]
    //   (bias|Ebf|Wbf contiguous -> one 6MB+4KB zero range)
    char* ws = (char*)d_ws;
    ushort* x2    = (ushort*)ws;
    float*  biasd = (float*)(ws + (20u << 20));
    ushort* Ebf   = (ushort*)(ws + (20u << 20) + 4096);
    ushort* Wbf   = (ushort*)(ws + (22u << 20) + 4096);

    // 1. zero biasd | Ebf | Wbf (contiguous 6 MB + 4 KB = 393472 float4)
    k_zero4<<<1537, 256, 0, stream>>>((float4*)biasd, 393472);

    // 2. x-cvt + direct-bf16 CAS scatter (E, W) + bias scatter (one launch)
    k_prep<<<2048 + NNZ_E / 256 + NNZ_W / 256 + NNZ_B / 256, 256, 0, stream>>>(
        (const float4*)x, x2,
        embed_rows, embed_cols, embed_vals,
        w_rows, w_cols, w_vals,
        bias_idx, bias_vals, Ebf, Wbf, biasd);

    // 3. GEMM-A': dual-B fused  {h = relu(x @ E^T)} + {out = x @ W_L^T + bias}
    k_gemmA<<<512, 256, 0, stream>>>(x2, Ebf, Wbf, biasd, out, x2 + F_IN);

    // 4. GEMM-B: out += h @ W_R^T
    k_gemmB<<<512, 256, 0, stream>>>(x2, Wbf, out);
}